// Round 1
// baseline (399.579 us; speedup 1.0000x reference)
//
#include <hip/hip_runtime.h>

typedef __attribute__((ext_vector_type(8))) short short8;
typedef __attribute__((ext_vector_type(4))) float float4v;

#define MFMA_BF16 __builtin_amdgcn_mfma_f32_16x16x32_bf16

__device__ __forceinline__ unsigned short f2b(float f) {
  union { float f; unsigned u; } v; v.f = f;
  unsigned r = v.u + 0x7FFFu + ((v.u >> 16) & 1u);  // round-to-nearest-even
  return (unsigned short)(r >> 16);
}

// Swizzled element index within a [rows][64] bf16 LDS tile.
// 16B-chunk swizzle: kb' = kb ^ (r&7) ^ ((r>>3)&7). Keeps 8-element (16B)
// chunks contiguous so b128 reads work; spreads banks so transpose/scatter
// writes are 2-way (free) and all b128 ops sit at the 8-cyc BW floor.
__device__ __forceinline__ int swa(int r, int k) {
  return (r << 6) + ((((k >> 3) ^ r ^ (r >> 3)) & 7) << 3) + (k & 7);
}

__global__ __launch_bounds__(256) void cast_f32_bf16(const float* __restrict__ src,
                                                     unsigned short* __restrict__ dst,
                                                     int n4) {
  int i = blockIdx.x * 256 + threadIdx.x;
  if (i >= n4) return;
  float4 f = ((const float4*)src)[i];
  ushort4 o;
  o.x = f2b(f.x); o.y = f2b(f.y); o.z = f2b(f.z); o.w = f2b(f.w);
  ((ushort4*)dst)[i] = o;
}

// C[m,n] = sum_k X[m,k] * W[n,k] + bias[n]  (i.e. y = x @ W^T + b), bf16 out.
// M=16384, N=768, K=768. 128x128 tile, BK=32, 4 waves (2x2), 4x4 MFMA frags.
__global__ __launch_bounds__(256) void qkv_gemm(
    const unsigned short* __restrict__ X, const unsigned short* __restrict__ Wall,
    const float* __restrict__ b0, const float* __restrict__ b1, const float* __restrict__ b2,
    unsigned short* __restrict__ O0, unsigned short* __restrict__ O1, unsigned short* __restrict__ O2) {
  __shared__ __align__(16) unsigned short As[128 * 32];
  __shared__ __align__(16) unsigned short Bs[128 * 32];
  const int z = blockIdx.z;
  const unsigned short* W = Wall + (size_t)z * 589824;
  const float* bias = (z == 0) ? b0 : (z == 1 ? b1 : b2);
  unsigned short* O = (z == 0) ? O0 : (z == 1 ? O1 : O2);
  const int m0 = blockIdx.x * 128, n0 = blockIdx.y * 128;
  const int t = threadIdx.x, w = t >> 6, l = t & 63, qd = l >> 4, col = l & 15;
  const int wm = (w & 1) * 64, wn = (w >> 1) * 64;

  float4v acc[4][4];
#pragma unroll
  for (int i = 0; i < 4; ++i)
#pragma unroll
    for (int j = 0; j < 4; ++j) acc[i][j] = (float4v)0.0f;

  const unsigned short* Xp = X + (size_t)m0 * 768;
  const unsigned short* Wp = W + (size_t)n0 * 768;

  const int c1 = 256 + t;
  const int r0 = t >> 2, cc0 = (t & 3) * 8;
  const int r1 = c1 >> 2, cc1 = (c1 & 3) * 8;

  for (int k0 = 0; k0 < 768; k0 += 32) {
    *(uint4*)&As[r0 * 32 + cc0] = *(const uint4*)&Xp[r0 * 768 + k0 + cc0];
    *(uint4*)&As[r1 * 32 + cc1] = *(const uint4*)&Xp[r1 * 768 + k0 + cc1];
    *(uint4*)&Bs[r0 * 32 + cc0] = *(const uint4*)&Wp[r0 * 768 + k0 + cc0];
    *(uint4*)&Bs[r1 * 32 + cc1] = *(const uint4*)&Wp[r1 * 768 + k0 + cc1];
    __syncthreads();
    short8 af[4], bf[4];
#pragma unroll
    for (int mi = 0; mi < 4; ++mi)
      af[mi] = *(const short8*)&As[(wm + mi * 16 + col) * 32 + qd * 8];
#pragma unroll
    for (int ni = 0; ni < 4; ++ni)
      bf[ni] = *(const short8*)&Bs[(wn + ni * 16 + col) * 32 + qd * 8];
#pragma unroll
    for (int mi = 0; mi < 4; ++mi)
#pragma unroll
      for (int ni = 0; ni < 4; ++ni)
        acc[mi][ni] = MFMA_BF16(af[mi], bf[ni], acc[mi][ni], 0, 0, 0);
    __syncthreads();
  }

#pragma unroll
  for (int ni = 0; ni < 4; ++ni) {
    const int n = n0 + wn + ni * 16 + col;
    const float bb = bias[n];
#pragma unroll
    for (int mi = 0; mi < 4; ++mi)
#pragma unroll
      for (int r = 0; r < 4; ++r) {
        const int m = m0 + wm + mi * 16 + qd * 4 + r;
        O[(size_t)m * 768 + n] = f2b(acc[mi][ni][r] + bb);
      }
  }
}

// Flash attention: one block per (q-tile of 128, head, batch). 4 waves, each
// owns 32 q rows. Tk=64. Q/K/V bf16 in [B*S, 768] layout, head offset h*64.
__global__ __launch_bounds__(256) void attn(
    const unsigned short* __restrict__ Q, const unsigned short* __restrict__ K,
    const unsigned short* __restrict__ V, float* __restrict__ O) {
  __shared__ __align__(16) unsigned short Qs[128 * 64];
  __shared__ __align__(16) unsigned short Ks[64 * 64];
  __shared__ __align__(16) unsigned short Vt[64 * 64];   // [d][k] transposed
  __shared__ __align__(16) unsigned short Pls[4][32 * 64];

  const int qt = blockIdx.x, h = blockIdx.y, b = blockIdx.z;
  const int q0 = qt * 128;
  const int t = threadIdx.x, w = t >> 6, l = t & 63, qd = l >> 4, col = l & 15;

  const unsigned short* Qg = Q + (size_t)(b * 1024 + q0) * 768 + h * 64;
#pragma unroll
  for (int p = 0; p < 4; ++p) {
    int c = p * 256 + t;
    int row = c >> 3, dg = (c & 7) * 8;
    *(uint4*)&Qs[swa(row, dg)] = *(const uint4*)&Qg[(size_t)row * 768 + dg];
  }

  float4v acc[2][4];
  float4v mrun[2], lrun[2];
#pragma unroll
  for (int mi = 0; mi < 2; ++mi) {
    mrun[mi] = (float4v)(-3.0e38f);
    lrun[mi] = (float4v)0.0f;
#pragma unroll
    for (int ni = 0; ni < 4; ++ni) acc[mi][ni] = (float4v)0.0f;
  }

  for (int kt = 0; kt < 16; ++kt) {
    const size_t kbase = (size_t)(b * 1024 + kt * 64) * 768 + h * 64;
    const unsigned short* Kg = K + kbase;
    const unsigned short* Vg = V + kbase;
#pragma unroll
    for (int p = 0; p < 2; ++p) {
      int c = p * 256 + t;
      int row = c >> 3, dg = (c & 7) * 8;
      *(uint4*)&Ks[swa(row, dg)] = *(const uint4*)&Kg[(size_t)row * 768 + dg];
    }
#pragma unroll
    for (int p = 0; p < 2; ++p) {
      int c = p * 256 + t;
      int dg = (c & 7) * 8, k = c >> 3;
      uint4 raw = *(const uint4*)&Vg[(size_t)k * 768 + dg];
      const unsigned short* e = (const unsigned short*)&raw;
#pragma unroll
      for (int j = 0; j < 8; ++j) Vt[swa(dg + j, k)] = e[j];
    }
    __syncthreads();

    // --- S = Q K^T ---
    float4v s[2][4];
#pragma unroll
    for (int mi = 0; mi < 2; ++mi)
#pragma unroll
      for (int ni = 0; ni < 4; ++ni) s[mi][ni] = (float4v)0.0f;

#pragma unroll
    for (int ks = 0; ks < 2; ++ks) {
      const int kk = ks * 32 + qd * 8;
      short8 a0 = *(const short8*)&Qs[swa(w * 32 + col, kk)];
      short8 a1 = *(const short8*)&Qs[swa(w * 32 + 16 + col, kk)];
#pragma unroll
      for (int ni = 0; ni < 4; ++ni) {
        short8 bb = *(const short8*)&Ks[swa(ni * 16 + col, kk)];
        s[0][ni] = MFMA_BF16(a0, bb, s[0][ni], 0, 0, 0);
        s[1][ni] = MFMA_BF16(a1, bb, s[1][ni], 0, 0, 0);
      }
    }

    // --- online softmax (C-layout: row = qd*4+r, col = lane&15) ---
#pragma unroll
    for (int mi = 0; mi < 2; ++mi) {
#pragma unroll
      for (int ni = 0; ni < 4; ++ni) s[mi][ni] *= 0.125f;  // 1/sqrt(64)
      float4v rmax;
#pragma unroll
      for (int r = 0; r < 4; ++r)
        rmax[r] = fmaxf(fmaxf(s[mi][0][r], s[mi][1][r]),
                        fmaxf(s[mi][2][r], s[mi][3][r]));
#pragma unroll
      for (int off = 1; off < 16; off <<= 1)
#pragma unroll
        for (int r = 0; r < 4; ++r)
          rmax[r] = fmaxf(rmax[r], __shfl_xor(rmax[r], off));
      float4v mnew, alpha, rsum;
#pragma unroll
      for (int r = 0; r < 4; ++r) {
        mnew[r] = fmaxf(mrun[mi][r], rmax[r]);
        alpha[r] = __expf(mrun[mi][r] - mnew[r]);
        rsum[r] = 0.0f;
      }
#pragma unroll
      for (int ni = 0; ni < 4; ++ni)
#pragma unroll
        for (int r = 0; r < 4; ++r) {
          float p = __expf(s[mi][ni][r] - mnew[r]);
          s[mi][ni][r] = p;
          rsum[r] += p;
        }
#pragma unroll
      for (int off = 1; off < 16; off <<= 1)
#pragma unroll
        for (int r = 0; r < 4; ++r) rsum[r] += __shfl_xor(rsum[r], off);
#pragma unroll
      for (int r = 0; r < 4; ++r) {
        lrun[mi][r] = lrun[mi][r] * alpha[r] + rsum[r];
        mrun[mi][r] = mnew[r];
      }
#pragma unroll
      for (int ni = 0; ni < 4; ++ni)
#pragma unroll
        for (int r = 0; r < 4; ++r) acc[mi][ni][r] *= alpha[r];
      // P: C-layout -> A-layout via per-wave LDS round trip
#pragma unroll
      for (int ni = 0; ni < 4; ++ni)
#pragma unroll
        for (int r = 0; r < 4; ++r)
          Pls[w][swa(mi * 16 + qd * 4 + r, ni * 16 + col)] = f2b(s[mi][ni][r]);
    }

    // --- ctx += P V ---
#pragma unroll
    for (int ks = 0; ks < 2; ++ks) {
      const int kk = ks * 32 + qd * 8;
      short8 p0 = *(const short8*)&Pls[w][swa(col, kk)];
      short8 p1 = *(const short8*)&Pls[w][swa(16 + col, kk)];
#pragma unroll
      for (int nd = 0; nd < 4; ++nd) {
        short8 vb = *(const short8*)&Vt[swa(nd * 16 + col, kk)];
        acc[0][nd] = MFMA_BF16(p0, vb, acc[0][nd], 0, 0, 0);
        acc[1][nd] = MFMA_BF16(p1, vb, acc[1][nd], 0, 0, 0);
      }
    }
    __syncthreads();
  }

  float* Og = O + (size_t)(b * 1024 + q0 + w * 32) * 768 + h * 64;
#pragma unroll
  for (int mi = 0; mi < 2; ++mi) {
    float4v rl;
#pragma unroll
    for (int r = 0; r < 4; ++r) rl[r] = 1.0f / lrun[mi][r];
#pragma unroll
    for (int nd = 0; nd < 4; ++nd)
#pragma unroll
      for (int r = 0; r < 4; ++r)
        Og[(size_t)(mi * 16 + qd * 4 + r) * 768 + nd * 16 + col] =
            acc[mi][nd][r] * rl[r];
  }
}

extern "C" void kernel_launch(void* const* d_in, const int* in_sizes, int n_in,
                              void* d_out, int out_size, void* d_ws, size_t ws_size,
                              hipStream_t stream) {
  const float* hs = (const float*)d_in[0];
  const float* Wq = (const float*)d_in[1];
  const float* bq = (const float*)d_in[2];
  const float* Wk = (const float*)d_in[3];
  const float* bk = (const float*)d_in[4];
  const float* Wv = (const float*)d_in[5];
  const float* bv = (const float*)d_in[6];
  float* out = (float*)d_out;
  char* ws = (char*)d_ws;

  // ws layout (bytes):
  //   Xbf   @ 0         : 16384*768*2  = 25165824
  //   Wbf   @ 25165824  : 3*768*768*2  =  3538944
  //   Qbf   @ 28704768  : 25165824
  //   Kbf   @ 53870592  : 25165824
  //   Vbf   @ 79036416  : 25165824   (end = 104202240)
  unsigned short* Xb = (unsigned short*)ws;
  unsigned short* Wb = (unsigned short*)(ws + 25165824);
  unsigned short* Qb = (unsigned short*)(ws + 28704768);
  unsigned short* Kb = (unsigned short*)(ws + 53870592);
  unsigned short* Vb = (unsigned short*)(ws + 79036416);

  cast_f32_bf16<<<12288, 256, 0, stream>>>(hs, Xb, 3145728);
  cast_f32_bf16<<<576, 256, 0, stream>>>(Wq, Wb, 147456);
  cast_f32_bf16<<<576, 256, 0, stream>>>(Wk, Wb + 589824, 147456);
  cast_f32_bf16<<<576, 256, 0, stream>>>(Wv, Wb + 1179648, 147456);

  qkv_gemm<<<dim3(128, 6, 3), 256, 0, stream>>>(Xb, Wb, bq, bk, bv, Qb, Kb, Vb);

  attn<<<dim3(8, 12, 16), 256, 0, stream>>>(Qb, Kb, Vb, out);
}